// Round 1
// 1097.505 us; speedup vs baseline: 1.1872x; 1.1872x over previous
//
#include <hip/hip_runtime.h>
#include <math.h>

#define N 4096
#define C 256
#define NC 1000

typedef float v4f __attribute__((ext_vector_type(4)));

static __device__ __forceinline__ v4f splat4(float s) {
    v4f r; r.x = s; r.y = s; r.z = s; r.w = s; return r;
}

// ---------------- norms: inv_n[i] = 1/||x_i|| ----------------
__global__ __launch_bounds__(256) void k_norm(const float* __restrict__ x,
                                              float* __restrict__ inv_n) {
    int w = threadIdx.x >> 6, lane = threadIdx.x & 63;
    int row = blockIdx.x * 4 + w;
    const float4* x4 = (const float4*)(x + row * C);
    float4 v = x4[lane];
    float s = v.x * v.x + v.y * v.y + v.z * v.z + v.w * v.w;
    #pragma unroll
    for (int off = 32; off; off >>= 1) s += __shfl_xor(s, off, 64);
    if (lane == 0) inv_n[row] = (s > 0.f) ? 1.0f / sqrtf(s) : 0.f;
}

// ---------------- argmax over logits (softmax is monotone) ----------------
__global__ __launch_bounds__(256) void k_argmax(const float* __restrict__ logits,
                                                int* __restrict__ cls) {
    int w = threadIdx.x >> 6, lane = threadIdx.x & 63;
    int row = blockIdx.x * 4 + w;
    const float* L = logits + (long)row * NC;
    float best = -3.402823466e38f;
    int bi = 0;
    #pragma unroll
    for (int k = 0; k < 16; k++) {
        int idx = lane + 64 * k;
        if (idx < NC) {
            float v = L[idx];
            if (v > best) { best = v; bi = idx; }   // strict > keeps first max
        }
    }
    #pragma unroll
    for (int off = 32; off; off >>= 1) {
        float ov = __shfl_xor(best, off, 64);
        int   oi = __shfl_xor(bi, off, 64);
        if (ov > best || (ov == best && oi < bi)) { best = ov; bi = oi; }
    }
    if (lane == 0) cls[row] = bi;
}

// ---------------- Z_part[kz] = sum over K-chunk of w_i * x[i,a] * x[i,b] ----------------
__global__ __launch_bounds__(256) void k_zpart(const float* __restrict__ x,
                                               const float* __restrict__ inv_n,
                                               float* __restrict__ part) {
    __shared__ float As[32][64];
    __shared__ float Bs[32][64];
    int t = threadIdx.x;
    int tx = t & 15, ty = t >> 4;
    int a0 = blockIdx.x * 64, b0 = blockIdx.y * 64;
    int k0 = blockIdx.z * 256;
    float acc[4][4] = {};
    for (int kk = 0; kk < 256; kk += 32) {
        #pragma unroll
        for (int r = 0; r < 8; r++) {
            int idx = r * 256 + t;
            int il = idx >> 6, col = idx & 63;
            int gi = k0 + kk + il;
            float wv = inv_n[gi];
            As[il][col] = x[gi * C + a0 + col] * wv;
            Bs[il][col] = x[gi * C + b0 + col];
        }
        __syncthreads();
        #pragma unroll 8
        for (int il = 0; il < 32; il++) {
            float4 a4 = *(const float4*)&As[il][4 * ty];
            float4 b4 = *(const float4*)&Bs[il][4 * tx];
            acc[0][0] += a4.x * b4.x; acc[0][1] += a4.x * b4.y; acc[0][2] += a4.x * b4.z; acc[0][3] += a4.x * b4.w;
            acc[1][0] += a4.y * b4.x; acc[1][1] += a4.y * b4.y; acc[1][2] += a4.y * b4.z; acc[1][3] += a4.y * b4.w;
            acc[2][0] += a4.z * b4.x; acc[2][1] += a4.z * b4.y; acc[2][2] += a4.z * b4.z; acc[2][3] += a4.z * b4.w;
            acc[3][0] += a4.w * b4.x; acc[3][1] += a4.w * b4.y; acc[3][2] += a4.w * b4.z; acc[3][3] += a4.w * b4.w;
        }
        __syncthreads();
    }
    float* P = part + (long)blockIdx.z * (C * C);
    #pragma unroll
    for (int p = 0; p < 4; p++)
        #pragma unroll
        for (int q = 0; q < 4; q++)
            P[(a0 + 4 * ty + p) * C + (b0 + 4 * tx + q)] = acc[p][q];
}

// ---------------- Z = sum_k Z_part[k] ----------------
__global__ __launch_bounds__(256) void k_zreduce(const float* __restrict__ part,
                                                 float* __restrict__ Z) {
    int i = blockIdx.x * 256 + threadIdx.x;   // 65536 total
    float s = 0.f;
    #pragma unroll
    for (int k = 0; k < 16; k++) s += part[k * (C * C) + i];
    Z[i] = s;
}

// ---------------- x_new[i,:] = inv_n[i] * (x[i,:] @ Z) + x[i,:] ----------------
// 8 rows per block (2 per wave); each Z element loaded once per wave, reused
// for 2 rows -> half the Z loads vs 1-row-per-wave; x rows staged in LDS.
__global__ __launch_bounds__(256) void k_agg(const float* __restrict__ x,
                                             const float* __restrict__ Z,
                                             const float* __restrict__ inv_n,
                                             float* __restrict__ xn) {
    __shared__ float xs[8][C];
    int t = threadIdx.x;
    int w = t >> 6, lane = t & 63;
    int r0 = blockIdx.x * 8;
    // stage 8 x-rows: 2048 floats = 512 float4 = 2 per thread
    #pragma unroll
    for (int q = 0; q < 2; q++) {
        int idx = q * 256 + t;                 // float4 index 0..511
        int row = idx >> 6, col4 = idx & 63;
        *(float4*)&xs[row][col4 * 4] = ((const float4*)(x + (long)(r0 + row) * C))[col4];
    }
    __syncthreads();
    int wr = w * 2;                            // wave's first row within block
    v4f acc[2] = {};
    const v4f* Z4 = (const v4f*)Z;
    #pragma unroll 8
    for (int a = 0; a < C; a++) {
        v4f z = Z4[a * 64 + lane];
        #pragma unroll
        for (int r = 0; r < 2; r++)
            acc[r] += splat4(xs[wr + r][a]) * z;
    }
    #pragma unroll
    for (int r = 0; r < 2; r++) {
        int row = r0 + wr + r;
        float inv = inv_n[row];
        v4f xv = *(const v4f*)&xs[wr + r][lane * 4];
        v4f res = acc[r] * splat4(inv) + xv;
        *(v4f*)(xn + (long)row * C + lane * 4) = res;
    }
}

// ---------------- prototypes: per-class mean of x_new ----------------
// ballot-bitmask version: build 4096-bit membership mask (64 u64 words) via
// __ballot, then visit only matching rows (~4 per class). Deterministic:
// summation order is fixed ascending row index.
__global__ __launch_bounds__(256) void k_proto(const float* __restrict__ xn,
                                               const int* __restrict__ cls,
                                               float* __restrict__ proto) {
    __shared__ unsigned long long bits[64];
    int t = threadIdx.x, c = blockIdx.x;
    int w = t >> 6, lane = t & 63;
    #pragma unroll
    for (int k = 0; k < 16; k++) {
        int wd = w * 16 + k;                   // word index 0..63
        unsigned long long m = __ballot(cls[wd * 64 + lane] == c);
        if (lane == 0) bits[wd] = m;
    }
    __syncthreads();
    float acc = 0.f;
    int cnt = 0;
    for (int wd = 0; wd < 64; wd++) {
        unsigned long long m = bits[wd];
        cnt += __popcll(m);
        while (m) {
            int b = __ffsll((long long)m) - 1;
            m &= m - 1;
            acc += xn[(long)(wd * 64 + b) * C + t];
        }
    }
    proto[c * C + t] = cnt ? acc / (float)cnt : 0.f;
}

// ---------------- inter[i,j,:] = proto[j,:] - proto[i,:] ----------------
// grid (250, 8): 2000 blocks (~31 waves/CU), 4 i per block (one per wave),
// 125-j chunk per block, unrolled x5 for load/store pipelining.
__global__ __launch_bounds__(256) void k_inter(const float* __restrict__ proto,
                                               float* __restrict__ out) {
    int w = threadIdx.x >> 6, lane = threadIdx.x & 63;
    int i = blockIdx.x * 4 + w;                // 250*4 = 1000
    int j0 = blockIdx.y * 125;                 // 8 chunks of 125
    const v4f* p4 = (const v4f*)proto;
    v4f pi = p4[i * 64 + lane];
    v4f* o4 = (v4f*)out + (long)i * NC * 64 + lane;
    #pragma unroll 5
    for (int j = j0; j < j0 + 125; j++) {
        v4f pj = p4[j * 64 + lane];
        __builtin_nontemporal_store(pj - pi, &o4[(long)j * 64]);
    }
}

extern "C" void kernel_launch(void* const* d_in, const int* in_sizes, int n_in,
                              void* d_out, int out_size, void* d_ws, size_t ws_size,
                              hipStream_t stream) {
    const float* x      = (const float*)d_in[0];   // [4096, 256]
    const float* logits = (const float*)d_in[1];   // [4096, 1000]

    float* ws    = (float*)d_ws;
    float* inv_n = ws;                  // [4096]
    int*   cls   = (int*)(ws + 4096);   // [4096]
    float* Z     = ws + 8192;           // [65536]
    float* part  = ws + 73728;          // [16*65536] -- dead after k_zreduce
    float* xn    = part;                // [4096*256] aliases part (disjoint lifetime)

    float* proto = (float*)d_out;             // [1000, 256]
    float* inter = (float*)d_out + NC * C;    // [1000, 1000, 256]

    k_norm   <<<1024, 256, 0, stream>>>(x, inv_n);
    k_argmax <<<1024, 256, 0, stream>>>(logits, cls);
    k_zpart  <<<dim3(4, 4, 16), 256, 0, stream>>>(x, inv_n, part);
    k_zreduce<<<C * C / 256, 256, 0, stream>>>(part, Z);
    k_agg    <<<512, 256, 0, stream>>>(x, Z, inv_n, xn);
    k_proto  <<<NC, 256, 0, stream>>>(xn, cls, proto);
    k_inter  <<<dim3(250, 8), 256, 0, stream>>>(proto, inter);
}